// Round 11
// baseline (846.224 us; speedup 1.0000x reference)
//
#include <hip/hip_runtime.h>

// AttackLSTM R11 — single-kernel cross-wave layer pipeline.
// B=256, T=512. a0:(1->64) a1,a2:(64->64) b0:(64->1) b1,b2:(1->1)
// Block b = batch element b. 4 waves on 4 SIMDs of one CU:
//   wave0: layer a0 at t=v    (hh-dot only; x scalar input)
//   wave1: layer a1 at t=v-1  (ih-dot on h_a0 + hh-dot)
//   wave2: layer a2 at t=v-2
//   wave3: b0 projection on h_a2 at t=v-3 + fused b0/b1/b2 chain + store
// lane = hid, all 4 gates in-lane (no DPP in a-layer dot). h exchanged via
// 128B fp16 double-buffered LDS slots; one lgkm-only barrier per step.
// Weights fp16 in VGPRs (4-8 rows/lane), waves_per_eu(1,1) for ~512-reg budget.

#define BB 256
#define TT 512

typedef _Float16 v2h __attribute__((ext_vector_type(2)));
typedef _Float16 v8h __attribute__((ext_vector_type(8)));

__device__ __forceinline__ float sig_(float x) {
  return __builtin_amdgcn_rcpf(1.f + __builtin_amdgcn_exp2f(-1.44269504f * x));
}
__device__ __forceinline__ float tanh_(float x) {
  return __builtin_fmaf(2.f, __builtin_amdgcn_rcpf(1.f + __builtin_amdgcn_exp2f(-2.88539008f * x)), -1.f);
}

// DPP quad_perm broadcast of quad-lane K to all 4 lanes of each quad.
template <int K>
__device__ __forceinline__ float qb_(float v) {
  return __int_as_float(__builtin_amdgcn_update_dpp(
      0, __float_as_int(v), (K | (K << 2) | (K << 4) | (K << 6)), 0xF, 0xF, true));
}

// Barrier that only waits on LDS ops (global loads/stores stay in flight).
__device__ __forceinline__ void ldsbar_() {
  asm volatile("s_waitcnt lgkmcnt(0)\n\ts_barrier" ::: "memory");
}

#if __has_builtin(__builtin_amdgcn_fdot2)
#define FDOT2(acc, a, b) (acc) = __builtin_amdgcn_fdot2((a), (b), (acc), false)
#else
#define FDOT2(acc, a, b) \
  (acc) = __builtin_fmaf((float)(a)[0], (float)(b)[0], \
          __builtin_fmaf((float)(a)[1], (float)(b)[1], (acc)))
#endif
#define KEEPP(a) asm volatile("" : "+v"(a))

// Read a 64-half vector from LDS (8x ds_read_b128, wave-uniform broadcast).
__device__ __forceinline__ void load_h64(const _Float16* p, v2h hv[32]) {
  const v8h* hp = reinterpret_cast<const v8h*>(p);
#pragma unroll
  for (int i = 0; i < 8; ++i) {
    v8h blk = hp[i];
#pragma unroll
    for (int k = 0; k < 4; ++k) hv[4 * i + k] = v2h{blk[2 * k], blk[2 * k + 1]};
  }
}

// Convert one fp32 weight row (64) to 32 v2h register pairs.
__device__ __forceinline__ void load_row16(const float* src, v2h dst[32]) {
  const float4* p = reinterpret_cast<const float4*>(src);
#pragma unroll
  for (int i = 0; i < 16; ++i) {
    float4 v = p[i];
    dst[2 * i]     = v2h{(_Float16)v.x, (_Float16)v.y};
    dst[2 * i + 1] = v2h{(_Float16)v.z, (_Float16)v.w};
  }
}

__global__ __attribute__((amdgpu_flat_work_group_size(256, 256),
                          amdgpu_waves_per_eu(1, 1)))
void lstm_fused_k(
    const float* __restrict__ x,
    const float* __restrict__ wih_a0, const float* __restrict__ whh_a0,
    const float* __restrict__ bih_a0, const float* __restrict__ bhh_a0,
    const float* __restrict__ wih_a1, const float* __restrict__ whh_a1,
    const float* __restrict__ bih_a1, const float* __restrict__ bhh_a1,
    const float* __restrict__ wih_a2, const float* __restrict__ whh_a2,
    const float* __restrict__ bih_a2, const float* __restrict__ bhh_a2,
    const float* __restrict__ wih_b0, const float* __restrict__ whh_b0,
    const float* __restrict__ bih_b0, const float* __restrict__ bhh_b0,
    const float* __restrict__ wih_b1, const float* __restrict__ whh_b1,
    const float* __restrict__ bih_b1, const float* __restrict__ bhh_b1,
    const float* __restrict__ wih_b2, const float* __restrict__ whh_b2,
    const float* __restrict__ bih_b2, const float* __restrict__ bhh_b2,
    float* __restrict__ out)  // [B,T]
{
  const int b = blockIdx.x;
  const int tid = threadIdx.x;
  const int wave = tid >> 6;
  const int lane = tid & 63;

  __shared__ _Float16 hbuf[3 * 2 * 64];  // [layer][slot][hid], 128 halfs/layer
  __shared__ float xs[TT];

  xs[tid] = x[(size_t)b * TT + tid];
  xs[tid + 256] = x[(size_t)b * TT + 256 + tid];
  if (tid < 192) reinterpret_cast<float*>(hbuf)[tid] = 0.f;

  // Per-wave weights in VGPRs.
  v2h wA[4][32];  // waves 0-2: w_hh rows q*64+lane; wave 3: wA[0] = wih_b0 row (lane&3)
  v2h wB[4][32];  // waves 1-2: w_ih rows q*64+lane
  float bias[4] = {0.f, 0.f, 0.f, 0.f};
  float wi0_[4] = {0.f, 0.f, 0.f, 0.f};
  float whb0[4] = {}, wi1b[4] = {}, wh1b[4] = {}, bb1[4] = {},
        wi2b[4] = {}, wh2b[4] = {}, bb2[4] = {};

  if (wave == 0) {
#pragma unroll
    for (int q = 0; q < 4; ++q) {
      const int row = q * 64 + lane;
      load_row16(whh_a0 + row * 64, wA[q]);
      bias[q] = bih_a0[row] + bhh_a0[row];
      wi0_[q] = wih_a0[row];
    }
#pragma unroll
    for (int q = 0; q < 4; ++q)
#pragma unroll
      for (int j = 0; j < 32; ++j) KEEPP(wA[q][j]);
  } else if (wave == 1) {
#pragma unroll
    for (int q = 0; q < 4; ++q) {
      const int row = q * 64 + lane;
      load_row16(whh_a1 + row * 64, wA[q]);
      load_row16(wih_a1 + row * 64, wB[q]);
      bias[q] = bih_a1[row] + bhh_a1[row];
    }
#pragma unroll
    for (int q = 0; q < 4; ++q)
#pragma unroll
      for (int j = 0; j < 32; ++j) { KEEPP(wA[q][j]); KEEPP(wB[q][j]); }
  } else if (wave == 2) {
#pragma unroll
    for (int q = 0; q < 4; ++q) {
      const int row = q * 64 + lane;
      load_row16(whh_a2 + row * 64, wA[q]);
      load_row16(wih_a2 + row * 64, wB[q]);
      bias[q] = bih_a2[row] + bhh_a2[row];
    }
#pragma unroll
    for (int q = 0; q < 4; ++q)
#pragma unroll
      for (int j = 0; j < 32; ++j) { KEEPP(wA[q][j]); KEEPP(wB[q][j]); }
  } else {
    const int q = lane & 3;  // gate row of w_ih_b0 (replicated per quad)
    load_row16(wih_b0 + q * 64, wA[0]);
    bias[0] = bih_b0[q] + bhh_b0[q];
#pragma unroll
    for (int k = 0; k < 4; ++k) {
      whb0[k] = whh_b0[k];
      wi1b[k] = wih_b1[k]; wh1b[k] = whh_b1[k]; bb1[k] = bih_b1[k] + bhh_b1[k];
      wi2b[k] = wih_b2[k]; wh2b[k] = whh_b2[k]; bb2[k] = bih_b2[k] + bhh_b2[k];
    }
#pragma unroll
    for (int j = 0; j < 32; ++j) KEEPP(wA[0][j]);
  }
  __syncthreads();

  float c = 0.f;  // a-layer cell state (waves 0-2, per-lane hid)
  float h0b = 0.f, c0b = 0.f, h1b = 0.f, c1b = 0.f, h2b = 0.f, c2b = 0.f;  // wave3

  for (int v = 0; v < TT + 3; ++v) {
    if (wave == 0) {
      const int t = v;
      if (t < TT) {
        v2h hv[32];
        load_h64(hbuf + 0 * 128 + ((t + 1) & 1) * 64, hv);  // h_a0(t-1)
        const float xv = xs[t];
        float p0 = __builtin_fmaf(wi0_[0], xv, bias[0]);
        float p1 = __builtin_fmaf(wi0_[1], xv, bias[1]);
        float p2 = __builtin_fmaf(wi0_[2], xv, bias[2]);
        float p3 = __builtin_fmaf(wi0_[3], xv, bias[3]);
#pragma unroll
        for (int j = 0; j < 32; ++j) {
          FDOT2(p0, wA[0][j], hv[j]); FDOT2(p1, wA[1][j], hv[j]);
          FDOT2(p2, wA[2][j], hv[j]); FDOT2(p3, wA[3][j], hv[j]);
        }
        float gi = sig_(p0), gf = sig_(p1), gg = tanh_(p2), go = sig_(p3);
        c = __builtin_fmaf(gf, c, gi * gg);
        float h = go * tanh_(c);
        hbuf[0 * 128 + (t & 1) * 64 + lane] = (_Float16)h;
      }
    } else if (wave == 1) {
      const int t = v - 1;
      if (t >= 0 && t < TT) {
        v2h hp[32], ho[32];
        load_h64(hbuf + 0 * 128 + (t & 1) * 64, hp);        // h_a0(t)
        load_h64(hbuf + 1 * 128 + ((t + 1) & 1) * 64, ho);  // h_a1(t-1)
        float p0 = bias[0], p1 = bias[1], p2 = bias[2], p3 = bias[3];
#pragma unroll
        for (int j = 0; j < 32; ++j) {
          FDOT2(p0, wB[0][j], hp[j]); FDOT2(p1, wB[1][j], hp[j]);
          FDOT2(p2, wB[2][j], hp[j]); FDOT2(p3, wB[3][j], hp[j]);
        }
#pragma unroll
        for (int j = 0; j < 32; ++j) {
          FDOT2(p0, wA[0][j], ho[j]); FDOT2(p1, wA[1][j], ho[j]);
          FDOT2(p2, wA[2][j], ho[j]); FDOT2(p3, wA[3][j], ho[j]);
        }
        float gi = sig_(p0), gf = sig_(p1), gg = tanh_(p2), go = sig_(p3);
        c = __builtin_fmaf(gf, c, gi * gg);
        float h = go * tanh_(c);
        hbuf[1 * 128 + (t & 1) * 64 + lane] = (_Float16)h;
      }
    } else if (wave == 2) {
      const int t = v - 2;
      if (t >= 0 && t < TT) {
        v2h hp[32], ho[32];
        load_h64(hbuf + 1 * 128 + (t & 1) * 64, hp);        // h_a1(t)
        load_h64(hbuf + 2 * 128 + ((t + 1) & 1) * 64, ho);  // h_a2(t-1)
        float p0 = bias[0], p1 = bias[1], p2 = bias[2], p3 = bias[3];
#pragma unroll
        for (int j = 0; j < 32; ++j) {
          FDOT2(p0, wB[0][j], hp[j]); FDOT2(p1, wB[1][j], hp[j]);
          FDOT2(p2, wB[2][j], hp[j]); FDOT2(p3, wB[3][j], hp[j]);
        }
#pragma unroll
        for (int j = 0; j < 32; ++j) {
          FDOT2(p0, wA[0][j], ho[j]); FDOT2(p1, wA[1][j], ho[j]);
          FDOT2(p2, wA[2][j], ho[j]); FDOT2(p3, wA[3][j], ho[j]);
        }
        float gi = sig_(p0), gf = sig_(p1), gg = tanh_(p2), go = sig_(p3);
        c = __builtin_fmaf(gf, c, gi * gg);
        float h = go * tanh_(c);
        hbuf[2 * 128 + (t & 1) * 64 + lane] = (_Float16)h;
      }
    } else {
      const int t = v - 3;
      if (t >= 0 && t < TT) {
        v2h hv[32];
        load_h64(hbuf + 2 * 128 + (t & 1) * 64, hv);  // h_a2(t)
        float pg = bias[0];
#pragma unroll
        for (int j = 0; j < 32; ++j) FDOT2(pg, wA[0][j], hv[j]);
        // gates live on lanes (4k..4k+3) of every quad -> quad broadcast
        float p_i = qb_<0>(pg), p_f = qb_<1>(pg), p_g = qb_<2>(pg), p_o = qb_<3>(pg);
        // b0 (all lanes redundantly)
        float i0 = sig_(__builtin_fmaf(whb0[0], h0b, p_i));
        float f0 = sig_(__builtin_fmaf(whb0[1], h0b, p_f));
        float g0 = tanh_(__builtin_fmaf(whb0[2], h0b, p_g));
        float o0 = sig_(__builtin_fmaf(whb0[3], h0b, p_o));
        c0b = __builtin_fmaf(f0, c0b, i0 * g0);
        h0b = o0 * tanh_(c0b);
        // b1
        float i1 = sig_(bb1[0] + __builtin_fmaf(wi1b[0], h0b, wh1b[0] * h1b));
        float f1 = sig_(bb1[1] + __builtin_fmaf(wi1b[1], h0b, wh1b[1] * h1b));
        float g1 = tanh_(bb1[2] + __builtin_fmaf(wi1b[2], h0b, wh1b[2] * h1b));
        float o1 = sig_(bb1[3] + __builtin_fmaf(wi1b[3], h0b, wh1b[3] * h1b));
        c1b = __builtin_fmaf(f1, c1b, i1 * g1);
        h1b = o1 * tanh_(c1b);
        // b2
        float i2 = sig_(bb2[0] + __builtin_fmaf(wi2b[0], h1b, wh2b[0] * h2b));
        float f2 = sig_(bb2[1] + __builtin_fmaf(wi2b[1], h1b, wh2b[1] * h2b));
        float g2 = tanh_(bb2[2] + __builtin_fmaf(wi2b[2], h1b, wh2b[2] * h2b));
        float o2 = sig_(bb2[3] + __builtin_fmaf(wi2b[3], h1b, wh2b[3] * h2b));
        c2b = __builtin_fmaf(f2, c2b, i2 * g2);
        h2b = o2 * tanh_(c2b);
        if (lane == 0) out[(size_t)b * TT + t] = h2b;
      }
    }
    ldsbar_();
  }
}

extern "C" void kernel_launch(void* const* d_in, const int* in_sizes, int n_in,
                              void* d_out, int out_size, void* d_ws, size_t ws_size,
                              hipStream_t stream) {
  const float* x      = (const float*)d_in[0];
  const float* wih_a0 = (const float*)d_in[1];
  const float* whh_a0 = (const float*)d_in[2];
  const float* bih_a0 = (const float*)d_in[3];
  const float* bhh_a0 = (const float*)d_in[4];
  const float* wih_a1 = (const float*)d_in[5];
  const float* whh_a1 = (const float*)d_in[6];
  const float* bih_a1 = (const float*)d_in[7];
  const float* bhh_a1 = (const float*)d_in[8];
  const float* wih_a2 = (const float*)d_in[9];
  const float* whh_a2 = (const float*)d_in[10];
  const float* bih_a2 = (const float*)d_in[11];
  const float* bhh_a2 = (const float*)d_in[12];
  const float* wih_b0 = (const float*)d_in[13];
  const float* whh_b0 = (const float*)d_in[14];
  const float* bih_b0 = (const float*)d_in[15];
  const float* bhh_b0 = (const float*)d_in[16];
  const float* wih_b1 = (const float*)d_in[17];
  const float* whh_b1 = (const float*)d_in[18];
  const float* bih_b1 = (const float*)d_in[19];
  const float* bhh_b1 = (const float*)d_in[20];
  const float* wih_b2 = (const float*)d_in[21];
  const float* whh_b2 = (const float*)d_in[22];
  const float* bih_b2 = (const float*)d_in[23];
  const float* bhh_b2 = (const float*)d_in[24];
  float* out = (float*)d_out;

  lstm_fused_k<<<BB, 256, 0, stream>>>(
      x,
      wih_a0, whh_a0, bih_a0, bhh_a0,
      wih_a1, whh_a1, bih_a1, bhh_a1,
      wih_a2, whh_a2, bih_a2, bhh_a2,
      wih_b0, whh_b0, bih_b0, bhh_b0,
      wih_b1, whh_b1, bih_b1, bhh_b1,
      wih_b2, whh_b2, bih_b2, bhh_b2,
      out);
}

// Round 12
// 541.963 us; speedup vs baseline: 1.5614x; 1.5614x over previous
//
#include <hip/hip_runtime.h>

// AttackLSTM R12 — single-kernel 6-wave layer pipeline, register-clean.
// R11 failed because waves needed 256+ weight VGPRs (arch cap 256) -> AGPR
// shuffling (~500cy/step of v_accvgpr_read). R12 gives every wave <=128
// weight VGPRs by splitting ih-projections into dedicated waves:
//   w0: a0 rec (hh)        t=v    -> h_a0[t]
//   w1: a1 ih-proj(h_a0)   t=v-1  -> pj0[t]
//   w2: a1 rec (hh+pj0)    t=v-2  -> h_a1[t]
//   w3: a2 ih-proj(h_a1)   t=v-3  -> pj1[t]
//   w4: a2 rec (hh+pj1)    t=v-4  -> h_a2[t]
//   w5: b0 row-dot(h_a2) + fused b0/b1/b2 chain + store   t=v-5
// All exchanges are 1-step skew through t-parity double-buffered LDS.
// One lgkm-only barrier per virtual step. 384 threads, 1 block/CU.

#define BB 256
#define TT 512

typedef _Float16 v2h __attribute__((ext_vector_type(2)));

__device__ __forceinline__ float sig_(float x) {
  return __builtin_amdgcn_rcpf(1.f + __builtin_amdgcn_exp2f(-1.44269504f * x));
}
__device__ __forceinline__ float tanh_(float x) {
  return __builtin_fmaf(2.f, __builtin_amdgcn_rcpf(1.f + __builtin_amdgcn_exp2f(-2.88539008f * x)), -1.f);
}

template <int K>
__device__ __forceinline__ float qb_(float v) {
  return __int_as_float(__builtin_amdgcn_update_dpp(
      0, __float_as_int(v), (K | (K << 2) | (K << 4) | (K << 6)), 0xF, 0xF, true));
}

__device__ __forceinline__ void ldsbar_() {
  asm volatile("s_waitcnt lgkmcnt(0)\n\ts_barrier" ::: "memory");
}

#if __has_builtin(__builtin_amdgcn_fdot2)
#define FDOT2(acc, a, b) (acc) = __builtin_amdgcn_fdot2((a), (b), (acc), false)
#else
#define FDOT2(acc, a, b) \
  (acc) = __builtin_fmaf((float)(a)[0], (float)(b)[0], \
          __builtin_fmaf((float)(a)[1], (float)(b)[1], (acc)))
#endif
#define KEEPP(a) asm volatile("" : "+v"(a))

__device__ __forceinline__ v2h bc2h_(int v) { return __builtin_bit_cast(v2h, v); }

// 64 halfs from LDS as 32 v2h via int4 reads (8x ds_read_b128, no pack ops).
__device__ __forceinline__ void load_h64(const _Float16* p, v2h hv[32]) {
  const int4* hp = reinterpret_cast<const int4*>(p);
#pragma unroll
  for (int i = 0; i < 8; ++i) {
    int4 blk = hp[i];
    hv[4 * i + 0] = bc2h_(blk.x);
    hv[4 * i + 1] = bc2h_(blk.y);
    hv[4 * i + 2] = bc2h_(blk.z);
    hv[4 * i + 3] = bc2h_(blk.w);
  }
}

// fp32 row of 64 -> 32 v2h.
__device__ __forceinline__ void load_row16(const float* src, v2h dst[32]) {
  const float4* p = reinterpret_cast<const float4*>(src);
#pragma unroll
  for (int i = 0; i < 16; ++i) {
    float4 v = p[i];
    dst[2 * i]     = v2h{(_Float16)v.x, (_Float16)v.y};
    dst[2 * i + 1] = v2h{(_Float16)v.z, (_Float16)v.w};
  }
}

__global__ __attribute__((amdgpu_flat_work_group_size(384, 384),
                          amdgpu_waves_per_eu(1, 2)))
void lstm_pipe_k(
    const float* __restrict__ x,
    const float* __restrict__ wih_a0, const float* __restrict__ whh_a0,
    const float* __restrict__ bih_a0, const float* __restrict__ bhh_a0,
    const float* __restrict__ wih_a1, const float* __restrict__ whh_a1,
    const float* __restrict__ bih_a1, const float* __restrict__ bhh_a1,
    const float* __restrict__ wih_a2, const float* __restrict__ whh_a2,
    const float* __restrict__ bih_a2, const float* __restrict__ bhh_a2,
    const float* __restrict__ wih_b0, const float* __restrict__ whh_b0,
    const float* __restrict__ bih_b0, const float* __restrict__ bhh_b0,
    const float* __restrict__ wih_b1, const float* __restrict__ whh_b1,
    const float* __restrict__ bih_b1, const float* __restrict__ bhh_b1,
    const float* __restrict__ wih_b2, const float* __restrict__ whh_b2,
    const float* __restrict__ bih_b2, const float* __restrict__ bhh_b2,
    float* __restrict__ out)  // [B,T]
{
  const int b = blockIdx.x;
  const int tid = threadIdx.x;
  const int wave = tid >> 6;
  const int lane = tid & 63;

  __shared__ _Float16 hh[3 * 2 * 64];   // [layer][slot][hid]
  __shared__ float pj[2 * 2 * 64 * 4];  // [proj][slot][hid][gate]
  __shared__ float xs[TT];

  for (int i = tid; i < TT; i += 384) xs[i] = x[(size_t)b * TT + i];
  if (tid < 192) reinterpret_cast<int*>(hh)[tid] = 0;

  // ---- per-wave weights (<=128 VGPRs each) ----
  v2h wt[4][32];
  float bias[4] = {0.f, 0.f, 0.f, 0.f};
  float wi0_[4] = {0.f, 0.f, 0.f, 0.f};
  float whb0[4] = {}, wi1b[4] = {}, wh1b[4] = {}, bb1[4] = {},
        wi2b[4] = {}, wh2b[4] = {}, bb2[4] = {};

  if (wave == 0) {
#pragma unroll
    for (int q = 0; q < 4; ++q) {
      const int row = q * 64 + lane;
      load_row16(whh_a0 + row * 64, wt[q]);
      bias[q] = bih_a0[row] + bhh_a0[row];
      wi0_[q] = wih_a0[row];
    }
  } else if (wave == 1) {
#pragma unroll
    for (int q = 0; q < 4; ++q) load_row16(wih_a1 + (q * 64 + lane) * 64, wt[q]);
  } else if (wave == 2) {
#pragma unroll
    for (int q = 0; q < 4; ++q) {
      const int row = q * 64 + lane;
      load_row16(whh_a1 + row * 64, wt[q]);
      bias[q] = bih_a1[row] + bhh_a1[row];
    }
  } else if (wave == 3) {
#pragma unroll
    for (int q = 0; q < 4; ++q) load_row16(wih_a2 + (q * 64 + lane) * 64, wt[q]);
  } else if (wave == 4) {
#pragma unroll
    for (int q = 0; q < 4; ++q) {
      const int row = q * 64 + lane;
      load_row16(whh_a2 + row * 64, wt[q]);
      bias[q] = bih_a2[row] + bhh_a2[row];
    }
  } else {
    const int q = lane & 3;
    load_row16(wih_b0 + q * 64, wt[0]);
    bias[0] = bih_b0[q] + bhh_b0[q];
#pragma unroll
    for (int k = 0; k < 4; ++k) {
      whb0[k] = whh_b0[k];
      wi1b[k] = wih_b1[k]; wh1b[k] = whh_b1[k]; bb1[k] = bih_b1[k] + bhh_b1[k];
      wi2b[k] = wih_b2[k]; wh2b[k] = whh_b2[k]; bb2[k] = bih_b2[k] + bhh_b2[k];
    }
  }
#pragma unroll
  for (int q = 0; q < 4; ++q)
#pragma unroll
    for (int j = 0; j < 32; ++j) KEEPP(wt[q][j]);
  __syncthreads();

  float c = 0.f;  // rec-wave cell state (per-lane hid)
  float h0b = 0.f, c0b = 0.f, h1b = 0.f, c1b = 0.f, h2b = 0.f, c2b = 0.f;

  for (int v = 0; v < TT + 5; ++v) {
    if (wave == 0) {
      const int t = v;
      if (t < TT) {
        v2h hv[32];
        load_h64(hh + 0 * 128 + ((t + 1) & 1) * 64, hv);  // h_a0(t-1)
        const float xv = xs[t];
        float p0 = __builtin_fmaf(wi0_[0], xv, bias[0]);
        float p1 = __builtin_fmaf(wi0_[1], xv, bias[1]);
        float p2 = __builtin_fmaf(wi0_[2], xv, bias[2]);
        float p3 = __builtin_fmaf(wi0_[3], xv, bias[3]);
#pragma unroll
        for (int j = 0; j < 32; ++j) {
          FDOT2(p0, wt[0][j], hv[j]); FDOT2(p1, wt[1][j], hv[j]);
          FDOT2(p2, wt[2][j], hv[j]); FDOT2(p3, wt[3][j], hv[j]);
        }
        float gi = sig_(p0), gf = sig_(p1), gg = tanh_(p2), go = sig_(p3);
        c = __builtin_fmaf(gf, c, gi * gg);
        hh[0 * 128 + (t & 1) * 64 + lane] = (_Float16)(go * tanh_(c));
      }
    } else if (wave == 1) {
      const int t = v - 1;
      if (t >= 0 && t < TT) {
        v2h hv[32];
        load_h64(hh + 0 * 128 + (t & 1) * 64, hv);  // h_a0(t)
        float p0 = 0.f, p1 = 0.f, p2 = 0.f, p3 = 0.f;
#pragma unroll
        for (int j = 0; j < 32; ++j) {
          FDOT2(p0, wt[0][j], hv[j]); FDOT2(p1, wt[1][j], hv[j]);
          FDOT2(p2, wt[2][j], hv[j]); FDOT2(p3, wt[3][j], hv[j]);
        }
        *reinterpret_cast<float4*>(&pj[(0 * 2 + (t & 1)) * 256 + lane * 4]) =
            float4{p0, p1, p2, p3};
      }
    } else if (wave == 2) {
      const int t = v - 2;
      if (t >= 0 && t < TT) {
        v2h hv[32];
        load_h64(hh + 1 * 128 + ((t + 1) & 1) * 64, hv);  // h_a1(t-1)
        float4 pr = *reinterpret_cast<const float4*>(
            &pj[(0 * 2 + (t & 1)) * 256 + lane * 4]);
        float p0 = bias[0] + pr.x, p1 = bias[1] + pr.y;
        float p2 = bias[2] + pr.z, p3 = bias[3] + pr.w;
#pragma unroll
        for (int j = 0; j < 32; ++j) {
          FDOT2(p0, wt[0][j], hv[j]); FDOT2(p1, wt[1][j], hv[j]);
          FDOT2(p2, wt[2][j], hv[j]); FDOT2(p3, wt[3][j], hv[j]);
        }
        float gi = sig_(p0), gf = sig_(p1), gg = tanh_(p2), go = sig_(p3);
        c = __builtin_fmaf(gf, c, gi * gg);
        hh[1 * 128 + (t & 1) * 64 + lane] = (_Float16)(go * tanh_(c));
      }
    } else if (wave == 3) {
      const int t = v - 3;
      if (t >= 0 && t < TT) {
        v2h hv[32];
        load_h64(hh + 1 * 128 + (t & 1) * 64, hv);  // h_a1(t)
        float p0 = 0.f, p1 = 0.f, p2 = 0.f, p3 = 0.f;
#pragma unroll
        for (int j = 0; j < 32; ++j) {
          FDOT2(p0, wt[0][j], hv[j]); FDOT2(p1, wt[1][j], hv[j]);
          FDOT2(p2, wt[2][j], hv[j]); FDOT2(p3, wt[3][j], hv[j]);
        }
        *reinterpret_cast<float4*>(&pj[(1 * 2 + (t & 1)) * 256 + lane * 4]) =
            float4{p0, p1, p2, p3};
      }
    } else if (wave == 4) {
      const int t = v - 4;
      if (t >= 0 && t < TT) {
        v2h hv[32];
        load_h64(hh + 2 * 128 + ((t + 1) & 1) * 64, hv);  // h_a2(t-1)
        float4 pr = *reinterpret_cast<const float4*>(
            &pj[(1 * 2 + (t & 1)) * 256 + lane * 4]);
        float p0 = bias[0] + pr.x, p1 = bias[1] + pr.y;
        float p2 = bias[2] + pr.z, p3 = bias[3] + pr.w;
#pragma unroll
        for (int j = 0; j < 32; ++j) {
          FDOT2(p0, wt[0][j], hv[j]); FDOT2(p1, wt[1][j], hv[j]);
          FDOT2(p2, wt[2][j], hv[j]); FDOT2(p3, wt[3][j], hv[j]);
        }
        float gi = sig_(p0), gf = sig_(p1), gg = tanh_(p2), go = sig_(p3);
        c = __builtin_fmaf(gf, c, gi * gg);
        hh[2 * 128 + (t & 1) * 64 + lane] = (_Float16)(go * tanh_(c));
      }
    } else {
      const int t = v - 5;
      if (t >= 0 && t < TT) {
        v2h hv[32];
        load_h64(hh + 2 * 128 + (t & 1) * 64, hv);  // h_a2(t)
        float pg = bias[0];
#pragma unroll
        for (int j = 0; j < 32; ++j) FDOT2(pg, wt[0][j], hv[j]);
        float p_i = qb_<0>(pg), p_f = qb_<1>(pg), p_g = qb_<2>(pg), p_o = qb_<3>(pg);
        float i0 = sig_(__builtin_fmaf(whb0[0], h0b, p_i));
        float f0 = sig_(__builtin_fmaf(whb0[1], h0b, p_f));
        float g0 = tanh_(__builtin_fmaf(whb0[2], h0b, p_g));
        float o0 = sig_(__builtin_fmaf(whb0[3], h0b, p_o));
        c0b = __builtin_fmaf(f0, c0b, i0 * g0);
        h0b = o0 * tanh_(c0b);
        float i1 = sig_(bb1[0] + __builtin_fmaf(wi1b[0], h0b, wh1b[0] * h1b));
        float f1 = sig_(bb1[1] + __builtin_fmaf(wi1b[1], h0b, wh1b[1] * h1b));
        float g1 = tanh_(bb1[2] + __builtin_fmaf(wi1b[2], h0b, wh1b[2] * h1b));
        float o1 = sig_(bb1[3] + __builtin_fmaf(wi1b[3], h0b, wh1b[3] * h1b));
        c1b = __builtin_fmaf(f1, c1b, i1 * g1);
        h1b = o1 * tanh_(c1b);
        float i2 = sig_(bb2[0] + __builtin_fmaf(wi2b[0], h1b, wh2b[0] * h2b));
        float f2 = sig_(bb2[1] + __builtin_fmaf(wi2b[1], h1b, wh2b[1] * h2b));
        float g2 = tanh_(bb2[2] + __builtin_fmaf(wi2b[2], h1b, wh2b[2] * h2b));
        float o2 = sig_(bb2[3] + __builtin_fmaf(wi2b[3], h1b, wh2b[3] * h2b));
        c2b = __builtin_fmaf(f2, c2b, i2 * g2);
        h2b = o2 * tanh_(c2b);
        if (lane == 0) out[(size_t)b * TT + t] = h2b;
      }
    }
    ldsbar_();
  }
}

extern "C" void kernel_launch(void* const* d_in, const int* in_sizes, int n_in,
                              void* d_out, int out_size, void* d_ws, size_t ws_size,
                              hipStream_t stream) {
  const float* x      = (const float*)d_in[0];
  const float* wih_a0 = (const float*)d_in[1];
  const float* whh_a0 = (const float*)d_in[2];
  const float* bih_a0 = (const float*)d_in[3];
  const float* bhh_a0 = (const float*)d_in[4];
  const float* wih_a1 = (const float*)d_in[5];
  const float* whh_a1 = (const float*)d_in[6];
  const float* bih_a1 = (const float*)d_in[7];
  const float* bhh_a1 = (const float*)d_in[8];
  const float* wih_a2 = (const float*)d_in[9];
  const float* whh_a2 = (const float*)d_in[10];
  const float* bih_a2 = (const float*)d_in[11];
  const float* bhh_a2 = (const float*)d_in[12];
  const float* wih_b0 = (const float*)d_in[13];
  const float* whh_b0 = (const float*)d_in[14];
  const float* bih_b0 = (const float*)d_in[15];
  const float* bhh_b0 = (const float*)d_in[16];
  const float* wih_b1 = (const float*)d_in[17];
  const float* whh_b1 = (const float*)d_in[18];
  const float* bih_b1 = (const float*)d_in[19];
  const float* bhh_b1 = (const float*)d_in[20];
  const float* wih_b2 = (const float*)d_in[21];
  const float* whh_b2 = (const float*)d_in[22];
  const float* bih_b2 = (const float*)d_in[23];
  const float* bhh_b2 = (const float*)d_in[24];
  float* out = (float*)d_out;

  lstm_pipe_k<<<BB, 384, 0, stream>>>(
      x,
      wih_a0, whh_a0, bih_a0, bhh_a0,
      wih_a1, whh_a1, bih_a1, bhh_a1,
      wih_a2, whh_a2, bih_a2, bhh_a2,
      wih_b0, whh_b0, bih_b0, bhh_b0,
      wih_b1, whh_b1, bih_b1, bhh_b1,
      wih_b2, whh_b2, bih_b2, bhh_b2,
      out);
}